// Round 3
// baseline (253.001 us; speedup 1.0000x reference)
//
#include <hip/hip_runtime.h>
#include <hip/hip_bf16.h>

// Fused: QKV proj (+bias) -> RoPE(Q,K) -> MHA softmax -> out proj (+bias)
// B=8 S=1024 D=1024 H=16 Dk=64.  GEMMs: bf16 MFMA 16x16x32, fp32 accum,
// 3-deep counted-vmcnt LDS pipeline (T3/T4), lane-linear LDS subtiling (no
// bank conflicts), XCD-swizzled grid (T1), setprio around MFMA (T5).

typedef __bf16 bf16_t;
typedef __bf16 bf16x8 __attribute__((ext_vector_type(8)));
typedef float  f32x4  __attribute__((ext_vector_type(4)));

static __device__ __forceinline__ f32x4 mfma16(bf16x8 a, bf16x8 b, f32x4 c) {
  return __builtin_amdgcn_mfma_f32_16x16x32_bf16(a, b, c, 0, 0, 0);
}
static __device__ __forceinline__ void gload_lds16(const void* g, void* l) {
  __builtin_amdgcn_global_load_lds((const __attribute__((address_space(1))) void*)g,
                                   (__attribute__((address_space(3))) void*)l,
                                   16, 0, 0);
}
#define VMCNT(n) asm volatile("s_waitcnt vmcnt(" #n ")" ::: "memory")
#define VMCNT0() asm volatile("s_waitcnt vmcnt(0)" ::: "memory")
#define SBAR() do { __builtin_amdgcn_sched_barrier(0); __builtin_amdgcn_s_barrier(); \
                    __builtin_amdgcn_sched_barrier(0); } while (0)

// ---------------- prep: fp32 -> bf16 cast (vectorized) ----------------
__global__ void k_cast(const float* __restrict__ s, bf16_t* __restrict__ d, int n4) {
  int i = blockIdx.x * 256 + threadIdx.x;
  if (i >= n4) return;
  float4 v = reinterpret_cast<const float4*>(s)[i];
  union { bf16_t b[4]; unsigned long long u; } pk;
  pk.b[0] = (bf16_t)v.x; pk.b[1] = (bf16_t)v.y;
  pk.b[2] = (bf16_t)v.z; pk.b[3] = (bf16_t)v.w;
  reinterpret_cast<unsigned long long*>(d)[i] = pk.u;
}

// ---------------- prep: rope table rt[s][f] = (cos, sin), f in [0,32) ----
__global__ void k_rope_table(const int* __restrict__ pos, float2* __restrict__ rt) {
  int s = blockIdx.x * 8 + (threadIdx.x >> 5);
  int f = threadIdx.x & 31;
  float p = (float)pos[s];
  float inv = powf(10000.0f, -(float)(2 * f) / 64.0f);
  float a = p * inv;
  rt[s * 32 + f] = make_float2(cosf(a), sinf(a));
}

// ============ pipelined GEMM core (BM=128, BN=256, BK=64, 3-deep) ============
// LDS layout per tile: slot s = grp*128 + kslot*16 + rlo  (16B slots)
//   row = grp*16 + rlo, k = kslot*8.  Fragment read (mi/ni, kh) for lane
//   (c,hi) is frag_base + lane*16  -> fully contiguous, conflict-free.
// Stage: linear LDS dest (t*16), permutation folded into global source addr.

#define GEMM_PIPE_BODY(KT_N)                                                     \
  f32x4 acc[4][4] = {};                                                          \
  stage(0, 0);                                                                   \
  stage(1, 1);                                                                   \
  VMCNT(6);                                                                      \
  SBAR();                                                                        \
  int b0 = 0, bs = 2;                                                            \
  const char* laW = (const char*)&LA[0][0] + wm2 * 4 * 2048 + hi * 256 + c * 16; \
  const char* lbW = (const char*)&LB[0][0] + wn4 * 4 * 2048 + hi * 256 + c * 16; \
  for (int u = 0; u < (KT_N); ++u) {                                             \
    if (u < (KT_N)-2) stage(bs, u + 2);                                          \
    const char* la = laW + b0 * 16384;                                           \
    const char* lb = lbW + b0 * 32768;                                           \
    bf16x8 af[4][2], bfr[4][2];                                                  \
    _Pragma("unroll")                                                            \
    for (int mi = 0; mi < 4; ++mi)                                               \
      _Pragma("unroll")                                                          \
      for (int kh = 0; kh < 2; ++kh)                                             \
        af[mi][kh] = *(const bf16x8*)(la + mi * 2048 + kh * 1024);               \
    _Pragma("unroll")                                                            \
    for (int ni = 0; ni < 4; ++ni)                                               \
      _Pragma("unroll")                                                          \
      for (int kh = 0; kh < 2; ++kh)                                             \
        bfr[ni][kh] = *(const bf16x8*)(lb + ni * 2048 + kh * 1024);              \
    __builtin_amdgcn_s_setprio(1);                                               \
    _Pragma("unroll")                                                            \
    for (int kh = 0; kh < 2; ++kh)                                               \
      _Pragma("unroll")                                                          \
      for (int mi = 0; mi < 4; ++mi)                                             \
        _Pragma("unroll")                                                        \
        for (int ni = 0; ni < 4; ++ni)                                           \
          acc[mi][ni] = mfma16(af[mi][kh], bfr[ni][kh], acc[mi][ni]);            \
    __builtin_amdgcn_s_setprio(0);                                               \
    if (u == (KT_N)-1) break;                                                    \
    if (u < (KT_N)-2) { VMCNT(6); } else { VMCNT0(); }                           \
    SBAR();                                                                      \
    b0 = (b0 == 2) ? 0 : b0 + 1;                                                 \
    bs = (bs == 2) ? 0 : bs + 1;                                                 \
  }

// ---------------- fused QKV GEMM: N=3072 (Wq|Wk|Wv concat) ----------------
// grid 768 blocks (32 m * 12 n * swizzle), 512 threads (8 waves 2Mx4N).
__global__ __launch_bounds__(512) void k_gemm_qkv(
    const bf16_t* __restrict__ Xb, const bf16_t* __restrict__ Wqkv,
    const float* __restrict__ bq, const float* __restrict__ bk,
    const float* __restrict__ bv, const float2* __restrict__ rt,
    bf16_t* __restrict__ Qh, bf16_t* __restrict__ Kh, bf16_t* __restrict__ Vt) {
  __shared__ alignas(16) bf16_t LA[3][128 * 64];
  __shared__ alignas(16) bf16_t LB[3][256 * 64];
  const int t = threadIdx.x;
  const int lane = t & 63, w = t >> 6;
  const int hi = lane >> 4, c = lane & 15;
  const int wm2 = w >> 2, wn4 = w & 3;

  // bijective XCD swizzle (768 % 8 == 0): each XCD gets 8 m-rows x 12 n-cols
  const int bid = blockIdx.x;
  const int wg = (bid & 7) * 96 + (bid >> 3);
  const int i0 = (wg / 12) * 128;
  const int e0 = (wg % 12) * 256;

  const bf16_t* ApA[2];
  const bf16_t* ApB[4];
#pragma unroll
  for (int l = 0; l < 2; ++l) {
    int s = l * 512 + t;
    int row = ((s >> 7) << 4) | (s & 15);
    int koff = ((s >> 4) & 7) * 8;
    ApA[l] = Xb + (size_t)(i0 + row) * 1024 + koff;
  }
#pragma unroll
  for (int l = 0; l < 4; ++l) {
    int s = l * 512 + t;
    int row = ((s >> 7) << 4) | (s & 15);
    int koff = ((s >> 4) & 7) * 8;
    ApB[l] = Wqkv + (size_t)(e0 + row) * 1024 + koff;
  }
  auto stage = [&](int bi, int kt) {
    char* da = (char*)&LA[bi][0] + t * 16;
    char* db = (char*)&LB[bi][0] + t * 16;
#pragma unroll
    for (int l = 0; l < 2; ++l) gload_lds16(ApA[l] + kt * 64, da + l * 8192);
#pragma unroll
    for (int l = 0; l < 4; ++l) gload_lds16(ApB[l] + kt * 64, db + l * 8192);
  };

  GEMM_PIPE_BODY(16)

  // ---- epilogue ----
  const int z = e0 >> 10;            // 0:Q 1:K 2:V  (BN=256 never crosses z)
  const int ez0 = (e0 & 1023) + wn4 * 64;
  const float* bias = (z == 0) ? bq : (z == 1) ? bk : bv;
  if (z == 2) {
#pragma unroll
    for (int mi = 0; mi < 4; ++mi) {
      int i = i0 + wm2 * 64 + mi * 16 + hi * 4;
      int b_ = i >> 10, s = i & 1023;
#pragma unroll
      for (int ni = 0; ni < 4; ++ni) {
        int ez = ez0 + ni * 16 + c;
        int h = ez >> 6, dk = ez & 63;
        float bv_ = bias[ez];
        union { bf16_t b[4]; unsigned long long u; } pk;
#pragma unroll
        for (int r = 0; r < 4; ++r) pk.b[r] = (bf16_t)(acc[mi][ni][r] + bv_);
        __builtin_memcpy(&Vt[((size_t)((b_ * 16 + h) * 64 + dk)) * 1024 + s], pk.b, 8);
      }
    }
  } else {
    bf16_t* O = (z == 0) ? Qh : Kh;
    const float scl = (z == 0) ? 0.125f : 1.0f;
#pragma unroll
    for (int mi = 0; mi < 4; ++mi) {
      int i = i0 + wm2 * 64 + mi * 16 + hi * 4;
      int b_ = i >> 10, sbase = i & 1023;
#pragma unroll
      for (int ni = 0; ni < 2; ++ni) {
        int ez = ez0 + ni * 16 + c;
        int h = ez >> 6, f = ez & 63;  // f < 32, partner frag ni+2 holds f+32
        float b1 = bias[ez], b2 = bias[ez + 32];
        size_t obase = (size_t)((b_ * 16 + h) * 1024);
#pragma unroll
        for (int r = 0; r < 4; ++r) {
          int s = sbase + r;
          float2 cs = rt[s * 32 + f];
          float q1 = acc[mi][ni][r] + b1;
          float q2 = acc[mi][ni + 2][r] + b2;
          O[(obase + s) * 64 + f] = (bf16_t)((q1 * cs.x - q2 * cs.y) * scl);
          O[(obase + s) * 64 + f + 32] = (bf16_t)((q1 * cs.y + q2 * cs.x) * scl);
        }
      }
    }
  }
}

// ---------------- out projection (same engine, fp32 +bias epilogue) --------
__global__ __launch_bounds__(512) void k_gemm_out(
    const bf16_t* __restrict__ Og, const bf16_t* __restrict__ Wob,
    const float* __restrict__ bo, float* __restrict__ out) {
  __shared__ alignas(16) bf16_t LA[3][128 * 64];
  __shared__ alignas(16) bf16_t LB[3][256 * 64];
  const int t = threadIdx.x;
  const int lane = t & 63, w = t >> 6;
  const int hi = lane >> 4, c = lane & 15;
  const int wm2 = w >> 2, wn4 = w & 3;

  const int bid = blockIdx.x;                 // 256 blocks, 32/XCD
  const int wg = (bid & 7) * 32 + (bid >> 3);
  const int i0 = (wg / 4) * 128;
  const int e0 = (wg % 4) * 256;

  const bf16_t* ApA[2];
  const bf16_t* ApB[4];
#pragma unroll
  for (int l = 0; l < 2; ++l) {
    int s = l * 512 + t;
    int row = ((s >> 7) << 4) | (s & 15);
    int koff = ((s >> 4) & 7) * 8;
    ApA[l] = Og + (size_t)(i0 + row) * 1024 + koff;
  }
#pragma unroll
  for (int l = 0; l < 4; ++l) {
    int s = l * 512 + t;
    int row = ((s >> 7) << 4) | (s & 15);
    int koff = ((s >> 4) & 7) * 8;
    ApB[l] = Wob + (size_t)(e0 + row) * 1024 + koff;
  }
  auto stage = [&](int bi, int kt) {
    char* da = (char*)&LA[bi][0] + t * 16;
    char* db = (char*)&LB[bi][0] + t * 16;
#pragma unroll
    for (int l = 0; l < 2; ++l) gload_lds16(ApA[l] + kt * 64, da + l * 8192);
#pragma unroll
    for (int l = 0; l < 4; ++l) gload_lds16(ApB[l] + kt * 64, db + l * 8192);
  };

  GEMM_PIPE_BODY(16)

#pragma unroll
  for (int mi = 0; mi < 4; ++mi) {
    int i = i0 + wm2 * 64 + mi * 16 + hi * 4;
#pragma unroll
    for (int ni = 0; ni < 4; ++ni) {
      int e = e0 + wn4 * 64 + ni * 16 + c;
      float bv_ = bo[e];
#pragma unroll
      for (int r = 0; r < 4; ++r)
        out[(size_t)(i + r) * 1024 + e] = acc[mi][ni][r] + bv_;
    }
  }
}

// ---------------- flash attention (unchanged from R2) ----------------
__global__ __launch_bounds__(256) void k_attn(
    const bf16_t* __restrict__ Qh, const bf16_t* __restrict__ Kh,
    const bf16_t* __restrict__ Vt, bf16_t* __restrict__ Og) {
  __shared__ alignas(16) bf16_t Ks[2][64][64];
  __shared__ alignas(16) bf16_t Vs[2][64][64];
  __shared__ alignas(16) bf16_t Pl[4][16][72];
  const int tid = threadIdx.x;
  const int lane = tid & 63, w = tid >> 6;
  const int hi = lane >> 4, c = lane & 15;
  const int bh = blockIdx.y;
  const int q0 = blockIdx.x * 64 + w * 16;
  const size_t base = (size_t)bh * 64 * 1024;

  bf16x8 qf[2];
  qf[0] = *(const bf16x8*)&Qh[base + (size_t)(q0 + c) * 64 + hi * 8];
  qf[1] = *(const bf16x8*)&Qh[base + (size_t)(q0 + c) * 64 + 32 + hi * 8];

  f32x4 o[4] = {};
  float m = -1e30f, lsum = 0.f;

  const int srow = tid >> 3;
  const int scg = tid & 7;
  const int sxor = srow & 7;
  auto stageK = [&](int bi, int k0) {
    char* dst = (char*)&Ks[bi][0][0] + tid * 16;
    gload_lds16(&Kh[base + (size_t)(k0 + srow) * 64 + ((scg ^ sxor) * 8)], dst);
    gload_lds16(&Kh[base + (size_t)(k0 + srow + 32) * 64 + ((scg ^ sxor) * 8)], dst + 4096);
  };
  auto stageV = [&](int bi, int k0) {
    char* dst = (char*)&Vs[bi][0][0] + tid * 16;
    gload_lds16(&Vt[base + (size_t)srow * 1024 + k0 + ((scg ^ sxor) * 8)], dst);
    gload_lds16(&Vt[base + (size_t)(srow + 32) * 1024 + k0 + ((scg ^ sxor) * 8)], dst + 4096);
  };

  stageK(0, 0);
  stageV(0, 0);
  VMCNT0();
  __syncthreads();
  int buf = 0;
  for (int t = 0; t < 16; ++t) {
    if (t + 1 < 16) { stageK(buf ^ 1, (t + 1) * 64); stageV(buf ^ 1, (t + 1) * 64); }
    f32x4 st[4] = {};
#pragma unroll
    for (int ni = 0; ni < 4; ++ni) {
#pragma unroll
      for (int kk = 0; kk < 2; ++kk) {
        int row = ni * 16 + c;
        int cg = kk * 4 + hi;
        bf16x8 kf = *(const bf16x8*)((const char*)&Ks[buf][0][0] + row * 128 +
                                     ((cg ^ (row & 7)) * 16));
        st[ni] = mfma16(kf, qf[kk], st[ni]);
      }
    }
    float pmax = -1e30f;
#pragma unroll
    for (int ni = 0; ni < 4; ++ni)
#pragma unroll
      for (int r = 0; r < 4; ++r) pmax = fmaxf(pmax, st[ni][r]);
    pmax = fmaxf(pmax, __shfl_xor(pmax, 16));
    pmax = fmaxf(pmax, __shfl_xor(pmax, 32));
    float mn = fmaxf(m, pmax);
    float scale = __expf(m - mn);
    m = mn;
    float psum = 0.f;
#pragma unroll
    for (int ni = 0; ni < 4; ++ni) {
      union { bf16_t b[4]; unsigned long long u; } pk;
#pragma unroll
      for (int r = 0; r < 4; ++r) {
        float p = __expf(st[ni][r] - mn);
        psum += p;
        pk.b[r] = (bf16_t)p;
      }
      __builtin_memcpy(&Pl[w][c][ni * 16 + hi * 4], pk.b, 8);
    }
    psum += __shfl_xor(psum, 16);
    psum += __shfl_xor(psum, 32);
    lsum = lsum * scale + psum;
#pragma unroll
    for (int r = 0; r < 4; ++r) {
      float sr = __shfl(scale, hi * 4 + r);
#pragma unroll
      for (int od = 0; od < 4; ++od) o[od][r] *= sr;
    }
    bf16x8 pa[2];
    __builtin_memcpy(&pa[0], &Pl[w][c][hi * 8], 16);
    __builtin_memcpy(&pa[1], &Pl[w][c][32 + hi * 8], 16);
#pragma unroll
    for (int od = 0; od < 4; ++od) {
#pragma unroll
      for (int kk = 0; kk < 2; ++kk) {
        int row = od * 16 + c;
        int cg = kk * 4 + hi;
        bf16x8 vf = *(const bf16x8*)((const char*)&Vs[buf][0][0] + row * 128 +
                                     ((cg ^ (row & 7)) * 16));
        o[od] = mfma16(pa[kk], vf, o[od]);
      }
    }
    VMCNT0();
    __syncthreads();
    buf ^= 1;
  }

  float invl = 1.0f / lsum;
  int b_ = bh >> 4, h = bh & 15;
#pragma unroll
  for (int r = 0; r < 4; ++r) {
    float ir = __shfl(invl, hi * 4 + r);
    int s = q0 + hi * 4 + r;
    size_t rowoff = ((size_t)(b_ * 1024 + s)) * 1024 + h * 64;
#pragma unroll
    for (int od = 0; od < 4; ++od)
      Og[rowoff + od * 16 + c] = (bf16_t)(o[od][r] * ir);
  }
}

extern "C" void kernel_launch(void* const* d_in, const int* in_sizes, int n_in,
                              void* d_out, int out_size, void* d_ws, size_t ws_size,
                              hipStream_t stream) {
  const float* x = (const float*)d_in[0];
  const int* pos = (const int*)d_in[1];
  const float* Wq = (const float*)d_in[2];
  const float* bq = (const float*)d_in[3];
  const float* Wk = (const float*)d_in[4];
  const float* bk = (const float*)d_in[5];
  const float* Wv = (const float*)d_in[6];
  const float* bv = (const float*)d_in[7];
  const float* Wo = (const float*)d_in[8];
  const float* bo = (const float*)d_in[9];
  float* out = (float*)d_out;

  // ws: [0,16M) Xb (reused as Og) | [16M,22M) Wqkv | [22M,24M) Wob
  //     [24M,40M) Vt | [42M,..) rope table.  Q,K live in d_out (32MB).
  char* ws = (char*)d_ws;
  bf16_t* Xb = (bf16_t*)ws;
  bf16_t* Wqkv = (bf16_t*)(ws + (16u << 20));
  bf16_t* Wob = (bf16_t*)(ws + (22u << 20));
  bf16_t* Vt = (bf16_t*)(ws + (24u << 20));
  float2* rt = (float2*)(ws + (42u << 20));
  bf16_t* Qh = (bf16_t*)d_out;
  bf16_t* Kh = (bf16_t*)d_out + (size_t)8 * 1024 * 1024;
  bf16_t* Og = Xb;

  k_cast<<<8192, 256, 0, stream>>>(x, Xb, 8192 * 1024 / 4);
  k_cast<<<1024, 256, 0, stream>>>(Wq, Wqkv, 1024 * 1024 / 4);
  k_cast<<<1024, 256, 0, stream>>>(Wk, Wqkv + (size_t)1024 * 1024, 1024 * 1024 / 4);
  k_cast<<<1024, 256, 0, stream>>>(Wv, Wqkv + (size_t)2048 * 1024, 1024 * 1024 / 4);
  k_cast<<<1024, 256, 0, stream>>>(Wo, Wob, 1024 * 1024 / 4);
  k_rope_table<<<128, 256, 0, stream>>>(pos, rt);

  k_gemm_qkv<<<768, 512, 0, stream>>>(Xb, Wqkv, bq, bk, bv, rt, Qh, Kh, Vt);
  k_attn<<<dim3(16, 128), 256, 0, stream>>>(Qh, Kh, Vt, Og);
  k_gemm_out<<<256, 512, 0, stream>>>(Og, Wob, bo, out);
}

// Round 4
// 226.219 us; speedup vs baseline: 1.1184x; 1.1184x over previous
//
#include <hip/hip_runtime.h>
#include <hip/hip_bf16.h>

// Fused: QKV proj (+bias) -> RoPE(Q,K) -> MHA softmax -> out proj (+bias)
// B=8 S=1024 D=1024 H=16 Dk=64.
// GEMM engine: 256x256 tile, BK=64, 8 waves (2Mx4N), 4-quadrant phase schedule
// (m201-style), counted vmcnt(8), stages into just-dead LDS regions of the same
// dbuf (race ledger in comments), lane-linear subtiled LDS (0 bank conflicts).

typedef __bf16 bf16_t;
typedef __bf16 bf16x8 __attribute__((ext_vector_type(8)));
typedef float  f32x4  __attribute__((ext_vector_type(4)));

static __device__ __forceinline__ f32x4 mfma16(bf16x8 a, bf16x8 b, f32x4 c) {
  return __builtin_amdgcn_mfma_f32_16x16x32_bf16(a, b, c, 0, 0, 0);
}
static __device__ __forceinline__ void gload_lds16(const void* g, void* l) {
  __builtin_amdgcn_global_load_lds((const __attribute__((address_space(1))) void*)g,
                                   (__attribute__((address_space(3))) void*)l,
                                   16, 0, 0);
}
#define VMCNT(n) asm volatile("s_waitcnt vmcnt(" #n ")" ::: "memory")
#define VMCNT0() asm volatile("s_waitcnt vmcnt(0)" ::: "memory")
#define LGKM0()  do { asm volatile("s_waitcnt lgkmcnt(0)" ::: "memory"); \
                      __builtin_amdgcn_sched_barrier(0); } while (0)
#define SBAR() do { __builtin_amdgcn_sched_barrier(0); __builtin_amdgcn_s_barrier(); \
                    __builtin_amdgcn_sched_barrier(0); } while (0)

// ---------------- prep kernels ----------------
__global__ void k_cast(const float* __restrict__ s, bf16_t* __restrict__ d, int n4) {
  int i = blockIdx.x * 256 + threadIdx.x;
  if (i >= n4) return;
  float4 v = reinterpret_cast<const float4*>(s)[i];
  union { bf16_t b[4]; unsigned long long u; } pk;
  pk.b[0] = (bf16_t)v.x; pk.b[1] = (bf16_t)v.y;
  pk.b[2] = (bf16_t)v.z; pk.b[3] = (bf16_t)v.w;
  reinterpret_cast<unsigned long long*>(d)[i] = pk.u;
}

__global__ void k_rope_table(const int* __restrict__ pos, float2* __restrict__ rt) {
  int s = blockIdx.x * 8 + (threadIdx.x >> 5);
  int f = threadIdx.x & 31;
  float p = (float)pos[s];
  float inv = powf(10000.0f, -(float)(2 * f) / 64.0f);
  float a = p * inv;
  rt[s * 32 + f] = make_float2(cosf(a), sinf(a));
}

// ============ 256x256 8-phase GEMM body (BK=64, K=1024, 16 K-tiles) ============
// LDS: A at [db][half] = db*32768 + half*16384 ; B at 65536 + same. Total 128KB.
// Half layout: slot = fr*128 + (kh*4+hi)*16 + c (16B slots); row=fr*16+c, k=(kh*4+hi)*8.
// Fragment reads are base + lane*16 -> conflict-free (R3 PMC: 0 conflicts).
// Race ledger (per K-tile j, dbuf d=j&1, phases p0..p3):
//   p0 reads A0(fr0-3)+B0(nc0-1) to regs; p1 reads B1(nc2-3); p2 reads A1(fr4-7).
//   B LDS dead after p1 trailing barrier, A LDS dead after p2 trailing barrier
//   (regs survive). Stage kt j+2 (same dbuf d): B at p2, A at p3 -> no WAR race.
//   vmcnt(8) at end of K-tile: newest 8 outstanding = j+2's stages, so j+1 resident.
#define GEMM256_BODY(Aptr, Bptr)                                               \
  __shared__ alignas(16) char LDSbuf[131072];                                  \
  const int t = threadIdx.x;                                                   \
  const int lane = t & 63, w = t >> 6;                                         \
  const int hi = lane >> 4, c = lane & 15;                                     \
  const int wm2 = w >> 2, wn4 = w & 3;                                         \
  const bf16_t* sA[2][2]; const bf16_t* sB[2][2];                              \
  _Pragma("unroll") for (int hf = 0; hf < 2; ++hf)                             \
    _Pragma("unroll") for (int l = 0; l < 2; ++l) {                            \
      int s_ = l * 512 + t;                                                    \
      int row = ((s_ >> 7) << 4) | (s_ & 15);                                  \
      int koff = ((s_ >> 4) & 7) * 8;                                          \
      sA[hf][l] = (Aptr) + (size_t)(i0 + hf * 128 + row) * 1024 + koff;        \
      sB[hf][l] = (Bptr) + (size_t)(e0 + hf * 128 + row) * 1024 + koff;        \
    }                                                                          \
  auto stA = [&](int db, int kt) {                                             \
    char* d0 = LDSbuf + db * 32768 + t * 16;                                   \
    gload_lds16(sA[0][0] + kt * 64, d0);                                       \
    gload_lds16(sA[0][1] + kt * 64, d0 + 8192);                                \
    gload_lds16(sA[1][0] + kt * 64, d0 + 16384);                               \
    gload_lds16(sA[1][1] + kt * 64, d0 + 24576);                               \
  };                                                                           \
  auto stB = [&](int db, int kt) {                                             \
    char* d0 = LDSbuf + 65536 + db * 32768 + t * 16;                           \
    gload_lds16(sB[0][0] + kt * 64, d0);                                       \
    gload_lds16(sB[0][1] + kt * 64, d0 + 8192);                                \
    gload_lds16(sB[1][0] + kt * 64, d0 + 16384);                               \
    gload_lds16(sB[1][1] + kt * 64, d0 + 24576);                               \
  };                                                                           \
  f32x4 acc[8][4] = {};                                                        \
  stA(0, 0); stB(0, 0); stA(1, 1); stB(1, 1);                                  \
  VMCNT(8); SBAR();                                                            \
  const char* laB = LDSbuf + wm2 * 16384 + hi * 256 + c * 16;                  \
  const char* lbB = LDSbuf + 65536 + (wn4 >> 1) * 16384 + (wn4 & 1) * 8192 +   \
                    hi * 256 + c * 16;                                         \
  _Pragma("unroll 2")                                                          \
  for (int j = 0; j < 16; ++j) {                                               \
    const char* la = laB + (j & 1) * 32768;                                    \
    const char* lb = lbB + (j & 1) * 32768;                                    \
    bf16x8 a0[4][2], a1[4][2], b0[2][2], b1[2][2];                             \
    /* ---- p0: A0+B0 reads, MFMA quad (fr0-3 x nc0-1) ---- */                 \
    _Pragma("unroll") for (int fr = 0; fr < 4; ++fr)                           \
      _Pragma("unroll") for (int kh = 0; kh < 2; ++kh)                         \
        a0[fr][kh] = *(const bf16x8*)(la + fr * 2048 + kh * 1024);             \
    _Pragma("unroll") for (int nc = 0; nc < 2; ++nc)                           \
      _Pragma("unroll") for (int kh = 0; kh < 2; ++kh)                         \
        b0[nc][kh] = *(const bf16x8*)(lb + nc * 2048 + kh * 1024);             \
    SBAR(); LGKM0();                                                           \
    __builtin_amdgcn_s_setprio(1);                                             \
    _Pragma("unroll") for (int kh = 0; kh < 2; ++kh)                           \
      _Pragma("unroll") for (int fr = 0; fr < 4; ++fr)                         \
        _Pragma("unroll") for (int nc = 0; nc < 2; ++nc)                       \
          acc[fr][nc] = mfma16(a0[fr][kh], b0[nc][kh], acc[fr][nc]);           \
    __builtin_amdgcn_s_setprio(0);                                             \
    SBAR();                                                                    \
    /* ---- p1: B1 reads, MFMA quad (fr0-3 x nc2-3) ---- */                    \
    _Pragma("unroll") for (int nc = 0; nc < 2; ++nc)                           \
      _Pragma("unroll") for (int kh = 0; kh < 2; ++kh)                         \
        b1[nc][kh] = *(const bf16x8*)(lb + (nc + 2) * 2048 + kh * 1024);       \
    SBAR(); LGKM0();                                                           \
    __builtin_amdgcn_s_setprio(1);                                             \
    _Pragma("unroll") for (int kh = 0; kh < 2; ++kh)                           \
      _Pragma("unroll") for (int fr = 0; fr < 4; ++fr)                         \
        _Pragma("unroll") for (int nc = 0; nc < 2; ++nc)                       \
          acc[fr][nc + 2] = mfma16(a0[fr][kh], b1[nc][kh], acc[fr][nc + 2]);   \
    __builtin_amdgcn_s_setprio(0);                                             \
    SBAR();                                                                    \
    /* ---- p2: A1 reads, stage B(j+2) [B LDS dead], MFMA (fr4-7 x nc0-1) */   \
    _Pragma("unroll") for (int fr = 0; fr < 4; ++fr)                           \
      _Pragma("unroll") for (int kh = 0; kh < 2; ++kh)                         \
        a1[fr][kh] = *(const bf16x8*)(la + (fr + 4) * 2048 + kh * 1024);       \
    if (j < 14) stB(j & 1, j + 2);                                             \
    SBAR(); LGKM0();                                                           \
    __builtin_amdgcn_s_setprio(1);                                             \
    _Pragma("unroll") for (int kh = 0; kh < 2; ++kh)                           \
      _Pragma("unroll") for (int fr = 0; fr < 4; ++fr)                         \
        _Pragma("unroll") for (int nc = 0; nc < 2; ++nc)                       \
          acc[fr + 4][nc] = mfma16(a1[fr][kh], b0[nc][kh], acc[fr + 4][nc]);   \
    __builtin_amdgcn_s_setprio(0);                                             \
    SBAR();                                                                    \
    /* ---- p3: stage A(j+2) [A LDS dead], MFMA (fr4-7 x nc2-3), K-tile sync */\
    if (j < 14) stA(j & 1, j + 2);                                             \
    SBAR(); LGKM0();                                                           \
    __builtin_amdgcn_s_setprio(1);                                             \
    _Pragma("unroll") for (int kh = 0; kh < 2; ++kh)                           \
      _Pragma("unroll") for (int fr = 0; fr < 4; ++fr)                         \
        _Pragma("unroll") for (int nc = 0; nc < 2; ++nc)                       \
          acc[fr + 4][nc + 2] = mfma16(a1[fr][kh], b1[nc][kh], acc[fr + 4][nc + 2]); \
    __builtin_amdgcn_s_setprio(0);                                             \
    if (j < 14) { VMCNT(8); } else if (j == 14) { VMCNT0(); }                  \
    SBAR();                                                                    \
  }

// ---------------- fused QKV GEMM: N=3072 (Wq|Wk|Wv concat) ----------------
// 384 blocks = 32 m-tiles x 12 n-tiles; XCD gets 4 consecutive m x all n.
__global__ __launch_bounds__(512) void k_gemm_qkv(
    const bf16_t* __restrict__ Xb, const bf16_t* __restrict__ Wqkv,
    const float* __restrict__ bq, const float* __restrict__ bk,
    const float* __restrict__ bv, const float2* __restrict__ rt,
    bf16_t* __restrict__ Qh, bf16_t* __restrict__ Kh, bf16_t* __restrict__ Vt) {
  const int bid = blockIdx.x;
  const int wg = (bid & 7) * 48 + (bid >> 3);
  const int i0 = (wg / 12) * 256;
  const int e0 = (wg % 12) * 256;

  GEMM256_BODY(Xb, Wqkv)

  const int z = e0 >> 10;            // 0:Q 1:K 2:V (BN=256 never crosses z)
  const int ez0 = (e0 & 1023) + wn4 * 64;
  const float* bias = (z == 0) ? bq : (z == 1) ? bk : bv;
  if (z == 2) {
#pragma unroll
    for (int fr = 0; fr < 8; ++fr) {
      int i = i0 + wm2 * 128 + fr * 16 + hi * 4;
      int b_ = i >> 10, s = i & 1023;
#pragma unroll
      for (int nc = 0; nc < 4; ++nc) {
        int ez = ez0 + nc * 16 + c;
        int h = ez >> 6, dk = ez & 63;
        float bv_ = bias[ez];
        union { bf16_t b[4]; unsigned long long u; } pk;
#pragma unroll
        for (int r = 0; r < 4; ++r) pk.b[r] = (bf16_t)(acc[fr][nc][r] + bv_);
        __builtin_memcpy(&Vt[((size_t)((b_ * 16 + h) * 64 + dk)) * 1024 + s], pk.b, 8);
      }
    }
  } else {
    bf16_t* O = (z == 0) ? Qh : Kh;
    const float scl = (z == 0) ? 0.125f : 1.0f;  // fold 1/sqrt(Dk) into Q
#pragma unroll
    for (int fr = 0; fr < 8; ++fr) {
      int i = i0 + wm2 * 128 + fr * 16 + hi * 4;
      int b_ = i >> 10, sbase = i & 1023;
#pragma unroll
      for (int nc = 0; nc < 2; ++nc) {  // f<32 ; partner f+32 in frag nc+2
        int ez = ez0 + nc * 16 + c;
        int h = ez >> 6, f = ez & 63;
        float b1_ = bias[ez], b2_ = bias[ez + 32];
        size_t obase = (size_t)((b_ * 16 + h) * 1024);
#pragma unroll
        for (int r = 0; r < 4; ++r) {
          int s = sbase + r;
          float2 cs = rt[s * 32 + f];
          float q1 = acc[fr][nc][r] + b1_;
          float q2 = acc[fr][nc + 2][r] + b2_;
          O[(obase + s) * 64 + f] = (bf16_t)((q1 * cs.x - q2 * cs.y) * scl);
          O[(obase + s) * 64 + f + 32] = (bf16_t)((q1 * cs.y + q2 * cs.x) * scl);
        }
      }
    }
  }
}

// ---------------- out projection (same engine) ----------------
// 128 blocks = 32 m x 4 n.
__global__ __launch_bounds__(512) void k_gemm_out(
    const bf16_t* __restrict__ Og, const bf16_t* __restrict__ Wob,
    const float* __restrict__ bo, float* __restrict__ out) {
  const int bid = blockIdx.x;
  const int wg = (bid & 7) * 16 + (bid >> 3);
  const int i0 = (wg >> 2) * 256;
  const int e0 = (wg & 3) * 256;

  GEMM256_BODY(Og, Wob)

#pragma unroll
  for (int fr = 0; fr < 8; ++fr) {
    int i = i0 + wm2 * 128 + fr * 16 + hi * 4;
#pragma unroll
    for (int nc = 0; nc < 4; ++nc) {
      int e = e0 + wn4 * 64 + nc * 16 + c;
      float bv_ = bo[e];
#pragma unroll
      for (int r = 0; r < 4; ++r)
        out[(size_t)(i + r) * 1024 + e] = acc[fr][nc][r] + bv_;
    }
  }
}

// ---------------- flash attention (unchanged from R2) ----------------
__global__ __launch_bounds__(256) void k_attn(
    const bf16_t* __restrict__ Qh, const bf16_t* __restrict__ Kh,
    const bf16_t* __restrict__ Vt, bf16_t* __restrict__ Og) {
  __shared__ alignas(16) bf16_t Ks[2][64][64];
  __shared__ alignas(16) bf16_t Vs[2][64][64];
  __shared__ alignas(16) bf16_t Pl[4][16][72];
  const int tid = threadIdx.x;
  const int lane = tid & 63, w = tid >> 6;
  const int hi = lane >> 4, c = lane & 15;
  const int bh = blockIdx.y;
  const int q0 = blockIdx.x * 64 + w * 16;
  const size_t base = (size_t)bh * 64 * 1024;

  bf16x8 qf[2];
  qf[0] = *(const bf16x8*)&Qh[base + (size_t)(q0 + c) * 64 + hi * 8];
  qf[1] = *(const bf16x8*)&Qh[base + (size_t)(q0 + c) * 64 + 32 + hi * 8];

  f32x4 o[4] = {};
  float m = -1e30f, lsum = 0.f;

  const int srow = tid >> 3;
  const int scg = tid & 7;
  const int sxor = srow & 7;
  auto stageK = [&](int bi, int k0) {
    char* dst = (char*)&Ks[bi][0][0] + tid * 16;
    gload_lds16(&Kh[base + (size_t)(k0 + srow) * 64 + ((scg ^ sxor) * 8)], dst);
    gload_lds16(&Kh[base + (size_t)(k0 + srow + 32) * 64 + ((scg ^ sxor) * 8)], dst + 4096);
  };
  auto stageV = [&](int bi, int k0) {
    char* dst = (char*)&Vs[bi][0][0] + tid * 16;
    gload_lds16(&Vt[base + (size_t)srow * 1024 + k0 + ((scg ^ sxor) * 8)], dst);
    gload_lds16(&Vt[base + (size_t)(srow + 32) * 1024 + k0 + ((scg ^ sxor) * 8)], dst + 4096);
  };

  stageK(0, 0);
  stageV(0, 0);
  VMCNT0();
  __syncthreads();
  int buf = 0;
  for (int t = 0; t < 16; ++t) {
    if (t + 1 < 16) { stageK(buf ^ 1, (t + 1) * 64); stageV(buf ^ 1, (t + 1) * 64); }
    f32x4 st[4] = {};
#pragma unroll
    for (int ni = 0; ni < 4; ++ni) {
#pragma unroll
      for (int kk = 0; kk < 2; ++kk) {
        int row = ni * 16 + c;
        int cg = kk * 4 + hi;
        bf16x8 kf = *(const bf16x8*)((const char*)&Ks[buf][0][0] + row * 128 +
                                     ((cg ^ (row & 7)) * 16));
        st[ni] = mfma16(kf, qf[kk], st[ni]);
      }
    }
    float pmax = -1e30f;
#pragma unroll
    for (int ni = 0; ni < 4; ++ni)
#pragma unroll
      for (int r = 0; r < 4; ++r) pmax = fmaxf(pmax, st[ni][r]);
    pmax = fmaxf(pmax, __shfl_xor(pmax, 16));
    pmax = fmaxf(pmax, __shfl_xor(pmax, 32));
    float mn = fmaxf(m, pmax);
    float scale = __expf(m - mn);
    m = mn;
    float psum = 0.f;
#pragma unroll
    for (int ni = 0; ni < 4; ++ni) {
      union { bf16_t b[4]; unsigned long long u; } pk;
#pragma unroll
      for (int r = 0; r < 4; ++r) {
        float p = __expf(st[ni][r] - mn);
        psum += p;
        pk.b[r] = (bf16_t)p;
      }
      __builtin_memcpy(&Pl[w][c][ni * 16 + hi * 4], pk.b, 8);
    }
    psum += __shfl_xor(psum, 16);
    psum += __shfl_xor(psum, 32);
    lsum = lsum * scale + psum;
#pragma unroll
    for (int r = 0; r < 4; ++r) {
      float sr = __shfl(scale, hi * 4 + r);
#pragma unroll
      for (int od = 0; od < 4; ++od) o[od][r] *= sr;
    }
    bf16x8 pa[2];
    __builtin_memcpy(&pa[0], &Pl[w][c][hi * 8], 16);
    __builtin_memcpy(&pa[1], &Pl[w][c][32 + hi * 8], 16);
#pragma unroll
    for (int od = 0; od < 4; ++od) {
#pragma unroll
      for (int kk = 0; kk < 2; ++kk) {
        int row = od * 16 + c;
        int cg = kk * 4 + hi;
        bf16x8 vf = *(const bf16x8*)((const char*)&Vs[buf][0][0] + row * 128 +
                                     ((cg ^ (row & 7)) * 16));
        o[od] = mfma16(pa[kk], vf, o[od]);
      }
    }
    VMCNT0();
    __syncthreads();
    buf ^= 1;
  }

  float invl = 1.0f / lsum;
  int b_ = bh >> 4, h = bh & 15;
#pragma unroll
  for (int r = 0; r < 4; ++r) {
    float ir = __shfl(invl, hi * 4 + r);
    int s = q0 + hi * 4 + r;
    size_t rowoff = ((size_t)(b_ * 1024 + s)) * 1024 + h * 64;
#pragma unroll
    for (int od = 0; od < 4; ++od)
      Og[rowoff + od * 16 + c] = (bf16_t)(o[od][r] * ir);
  }
}

extern "C" void kernel_launch(void* const* d_in, const int* in_sizes, int n_in,
                              void* d_out, int out_size, void* d_ws, size_t ws_size,
                              hipStream_t stream) {
  const float* x = (const float*)d_in[0];
  const int* pos = (const int*)d_in[1];
  const float* Wq = (const float*)d_in[2];
  const float* bq = (const float*)d_in[3];
  const float* Wk = (const float*)d_in[4];
  const float* bk = (const float*)d_in[5];
  const float* Wv = (const float*)d_in[6];
  const float* bv = (const float*)d_in[7];
  const float* Wo = (const float*)d_in[8];
  const float* bo = (const float*)d_in[9];
  float* out = (float*)d_out;

  // ws: [0,16M) Xb (reused as Og) | [16M,22M) Wqkv | [22M,24M) Wob
  //     [24M,40M) Vt | [42M,..) rope table.  Q,K live in d_out (32MB).
  char* ws = (char*)d_ws;
  bf16_t* Xb = (bf16_t*)ws;
  bf16_t* Wqkv = (bf16_t*)(ws + (16u << 20));
  bf16_t* Wob = (bf16_t*)(ws + (22u << 20));
  bf16_t* Vt = (bf16_t*)(ws + (24u << 20));
  float2* rt = (float2*)(ws + (42u << 20));
  bf16_t* Qh = (bf16_t*)d_out;
  bf16_t* Kh = (bf16_t*)d_out + (size_t)8 * 1024 * 1024;
  bf16_t* Og = Xb;

  k_cast<<<8192, 256, 0, stream>>>(x, Xb, 8192 * 1024 / 4);
  k_cast<<<1024, 256, 0, stream>>>(Wq, Wqkv, 1024 * 1024 / 4);
  k_cast<<<1024, 256, 0, stream>>>(Wk, Wqkv + (size_t)1024 * 1024, 1024 * 1024 / 4);
  k_cast<<<1024, 256, 0, stream>>>(Wv, Wqkv + (size_t)2048 * 1024, 1024 * 1024 / 4);
  k_cast<<<1024, 256, 0, stream>>>(Wo, Wob, 1024 * 1024 / 4);
  k_rope_table<<<128, 256, 0, stream>>>(pos, rt);

  k_gemm_qkv<<<384, 512, 0, stream>>>(Xb, Wqkv, bq, bk, bv, rt, Qh, Kh, Vt);
  k_attn<<<dim3(16, 128), 256, 0, stream>>>(Qh, Kh, Vt, Og);
  k_gemm_out<<<128, 512, 0, stream>>>(Og, Wob, bo, out);
}

// Round 5
// 203.091 us; speedup vs baseline: 1.2458x; 1.1139x over previous
//
#include <hip/hip_runtime.h>
#include <hip/hip_bf16.h>

// Fused: QKV proj (+bias) -> RoPE(Q,K) -> MHA softmax -> out proj (+bias)
// B=8 S=1024 D=1024 H=16 Dk=64.
// GEMM engine: 256x256 tile, 8-phase schedule, counted vmcnt(8) (R4, verified).
// Attn: 8-wave blocks, lane-linear subtiled K/V LDS (0-conflict), 3-buf vmcnt(2)
// pipeline, swapped PV (per-lane softmax stats, no shuffles), exp2 domain.

typedef __bf16 bf16_t;
typedef __bf16 bf16x8 __attribute__((ext_vector_type(8)));
typedef float  f32x4  __attribute__((ext_vector_type(4)));

static __device__ __forceinline__ f32x4 mfma16(bf16x8 a, bf16x8 b, f32x4 c) {
  return __builtin_amdgcn_mfma_f32_16x16x32_bf16(a, b, c, 0, 0, 0);
}
static __device__ __forceinline__ void gload_lds16(const void* g, void* l) {
  __builtin_amdgcn_global_load_lds((const __attribute__((address_space(1))) void*)g,
                                   (__attribute__((address_space(3))) void*)l,
                                   16, 0, 0);
}
#define VMCNT(n) asm volatile("s_waitcnt vmcnt(" #n ")" ::: "memory")
#define VMCNT0() asm volatile("s_waitcnt vmcnt(0)" ::: "memory")
#define LGKM0()  do { asm volatile("s_waitcnt lgkmcnt(0)" ::: "memory"); \
                      __builtin_amdgcn_sched_barrier(0); } while (0)
#define SBAR() do { __builtin_amdgcn_sched_barrier(0); __builtin_amdgcn_s_barrier(); \
                    __builtin_amdgcn_sched_barrier(0); } while (0)

#if __has_builtin(__builtin_amdgcn_exp2f)
#define EXP2F(x) __builtin_amdgcn_exp2f(x)
#else
#define EXP2F(x) exp2f(x)
#endif

// ---------------- prep kernels ----------------
__global__ void k_cast(const float* __restrict__ s, bf16_t* __restrict__ d, int n4) {
  int i = blockIdx.x * 256 + threadIdx.x;
  if (i >= n4) return;
  float4 v = reinterpret_cast<const float4*>(s)[i];
  union { bf16_t b[4]; unsigned long long u; } pk;
  pk.b[0] = (bf16_t)v.x; pk.b[1] = (bf16_t)v.y;
  pk.b[2] = (bf16_t)v.z; pk.b[3] = (bf16_t)v.w;
  reinterpret_cast<unsigned long long*>(d)[i] = pk.u;
}

__global__ void k_rope_table(const int* __restrict__ pos, float2* __restrict__ rt) {
  int s = blockIdx.x * 8 + (threadIdx.x >> 5);
  int f = threadIdx.x & 31;
  float p = (float)pos[s];
  float inv = powf(10000.0f, -(float)(2 * f) / 64.0f);
  float a = p * inv;
  rt[s * 32 + f] = make_float2(cosf(a), sinf(a));
}

// ============ 256x256 8-phase GEMM body (BK=64, K=1024, 16 K-tiles) ============
// (R4 engine, verified: MfmaUtil up, conflicts 0. See R4 race ledger.)
#define GEMM256_BODY(Aptr, Bptr)                                               \
  __shared__ alignas(16) char LDSbuf[131072];                                  \
  const int t = threadIdx.x;                                                   \
  const int lane = t & 63, w = t >> 6;                                         \
  const int hi = lane >> 4, c = lane & 15;                                     \
  const int wm2 = w >> 2, wn4 = w & 3;                                         \
  const bf16_t* sA[2][2]; const bf16_t* sB[2][2];                              \
  _Pragma("unroll") for (int hf = 0; hf < 2; ++hf)                             \
    _Pragma("unroll") for (int l = 0; l < 2; ++l) {                            \
      int s_ = l * 512 + t;                                                    \
      int row = ((s_ >> 7) << 4) | (s_ & 15);                                  \
      int koff = ((s_ >> 4) & 7) * 8;                                          \
      sA[hf][l] = (Aptr) + (size_t)(i0 + hf * 128 + row) * 1024 + koff;        \
      sB[hf][l] = (Bptr) + (size_t)(e0 + hf * 128 + row) * 1024 + koff;        \
    }                                                                          \
  auto stA = [&](int db, int kt) {                                             \
    char* d0 = LDSbuf + db * 32768 + t * 16;                                   \
    gload_lds16(sA[0][0] + kt * 64, d0);                                       \
    gload_lds16(sA[0][1] + kt * 64, d0 + 8192);                                \
    gload_lds16(sA[1][0] + kt * 64, d0 + 16384);                               \
    gload_lds16(sA[1][1] + kt * 64, d0 + 24576);                               \
  };                                                                           \
  auto stB = [&](int db, int kt) {                                             \
    char* d0 = LDSbuf + 65536 + db * 32768 + t * 16;                           \
    gload_lds16(sB[0][0] + kt * 64, d0);                                       \
    gload_lds16(sB[0][1] + kt * 64, d0 + 8192);                                \
    gload_lds16(sB[1][0] + kt * 64, d0 + 16384);                               \
    gload_lds16(sB[1][1] + kt * 64, d0 + 24576);                               \
  };                                                                           \
  f32x4 acc[8][4] = {};                                                        \
  stA(0, 0); stB(0, 0); stA(1, 1); stB(1, 1);                                  \
  VMCNT(8); SBAR();                                                            \
  const char* laB = LDSbuf + wm2 * 16384 + hi * 256 + c * 16;                  \
  const char* lbB = LDSbuf + 65536 + (wn4 >> 1) * 16384 + (wn4 & 1) * 8192 +   \
                    hi * 256 + c * 16;                                         \
  _Pragma("unroll 2")                                                          \
  for (int j = 0; j < 16; ++j) {                                               \
    const char* la = laB + (j & 1) * 32768;                                    \
    const char* lb = lbB + (j & 1) * 32768;                                    \
    bf16x8 a0[4][2], a1[4][2], b0[2][2], b1[2][2];                             \
    _Pragma("unroll") for (int fr = 0; fr < 4; ++fr)                           \
      _Pragma("unroll") for (int kh = 0; kh < 2; ++kh)                         \
        a0[fr][kh] = *(const bf16x8*)(la + fr * 2048 + kh * 1024);             \
    _Pragma("unroll") for (int nc = 0; nc < 2; ++nc)                           \
      _Pragma("unroll") for (int kh = 0; kh < 2; ++kh)                         \
        b0[nc][kh] = *(const bf16x8*)(lb + nc * 2048 + kh * 1024);             \
    SBAR(); LGKM0();                                                           \
    __builtin_amdgcn_s_setprio(1);                                             \
    _Pragma("unroll") for (int kh = 0; kh < 2; ++kh)                           \
      _Pragma("unroll") for (int fr = 0; fr < 4; ++fr)                         \
        _Pragma("unroll") for (int nc = 0; nc < 2; ++nc)                       \
          acc[fr][nc] = mfma16(a0[fr][kh], b0[nc][kh], acc[fr][nc]);           \
    __builtin_amdgcn_s_setprio(0);                                             \
    SBAR();                                                                    \
    _Pragma("unroll") for (int nc = 0; nc < 2; ++nc)                           \
      _Pragma("unroll") for (int kh = 0; kh < 2; ++kh)                         \
        b1[nc][kh] = *(const bf16x8*)(lb + (nc + 2) * 2048 + kh * 1024);       \
    SBAR(); LGKM0();                                                           \
    __builtin_amdgcn_s_setprio(1);                                             \
    _Pragma("unroll") for (int kh = 0; kh < 2; ++kh)                           \
      _Pragma("unroll") for (int fr = 0; fr < 4; ++fr)                         \
        _Pragma("unroll") for (int nc = 0; nc < 2; ++nc)                       \
          acc[fr][nc + 2] = mfma16(a0[fr][kh], b1[nc][kh], acc[fr][nc + 2]);   \
    __builtin_amdgcn_s_setprio(0);                                             \
    SBAR();                                                                    \
    _Pragma("unroll") for (int fr = 0; fr < 4; ++fr)                           \
      _Pragma("unroll") for (int kh = 0; kh < 2; ++kh)                         \
        a1[fr][kh] = *(const bf16x8*)(la + (fr + 4) * 2048 + kh * 1024);       \
    if (j < 14) stB(j & 1, j + 2);                                             \
    SBAR(); LGKM0();                                                           \
    __builtin_amdgcn_s_setprio(1);                                             \
    _Pragma("unroll") for (int kh = 0; kh < 2; ++kh)                           \
      _Pragma("unroll") for (int fr = 0; fr < 4; ++fr)                         \
        _Pragma("unroll") for (int nc = 0; nc < 2; ++nc)                       \
          acc[fr + 4][nc] = mfma16(a1[fr][kh], b0[nc][kh], acc[fr + 4][nc]);   \
    __builtin_amdgcn_s_setprio(0);                                             \
    SBAR();                                                                    \
    if (j < 14) stA(j & 1, j + 2);                                             \
    SBAR(); LGKM0();                                                           \
    __builtin_amdgcn_s_setprio(1);                                             \
    _Pragma("unroll") for (int kh = 0; kh < 2; ++kh)                           \
      _Pragma("unroll") for (int fr = 0; fr < 4; ++fr)                         \
        _Pragma("unroll") for (int nc = 0; nc < 2; ++nc)                       \
          acc[fr + 4][nc + 2] = mfma16(a1[fr][kh], b1[nc][kh], acc[fr + 4][nc + 2]); \
    __builtin_amdgcn_s_setprio(0);                                             \
    if (j < 14) { VMCNT(8); } else if (j == 14) { VMCNT0(); }                  \
    SBAR();                                                                    \
  }

// ---------------- fused QKV GEMM: N=3072 (Wq|Wk|Wv concat) ----------------
__global__ __launch_bounds__(512) void k_gemm_qkv(
    const bf16_t* __restrict__ Xb, const bf16_t* __restrict__ Wqkv,
    const float* __restrict__ bq, const float* __restrict__ bk,
    const float* __restrict__ bv, const float2* __restrict__ rt,
    bf16_t* __restrict__ Qh, bf16_t* __restrict__ Kh, bf16_t* __restrict__ Vt) {
  const int bid = blockIdx.x;
  const int wg = (bid & 7) * 48 + (bid >> 3);
  const int i0 = (wg / 12) * 256;
  const int e0 = (wg % 12) * 256;

  GEMM256_BODY(Xb, Wqkv)

  const int z = e0 >> 10;
  const int ez0 = (e0 & 1023) + wn4 * 64;
  const float* bias = (z == 0) ? bq : (z == 1) ? bk : bv;
  if (z == 2) {
#pragma unroll
    for (int fr = 0; fr < 8; ++fr) {
      int i = i0 + wm2 * 128 + fr * 16 + hi * 4;
      int b_ = i >> 10, s = i & 1023;
#pragma unroll
      for (int nc = 0; nc < 4; ++nc) {
        int ez = ez0 + nc * 16 + c;
        int h = ez >> 6, dk = ez & 63;
        float bv_ = bias[ez];
        union { bf16_t b[4]; unsigned long long u; } pk;
#pragma unroll
        for (int r = 0; r < 4; ++r) pk.b[r] = (bf16_t)(acc[fr][nc][r] + bv_);
        __builtin_memcpy(&Vt[((size_t)((b_ * 16 + h) * 64 + dk)) * 1024 + s], pk.b, 8);
      }
    }
  } else {
    bf16_t* O = (z == 0) ? Qh : Kh;
    // Q folds 1/sqrt(64) * log2(e) so attn softmax runs in exp2 domain.
    const float scl = (z == 0) ? 0.18033688011112042f : 1.0f;
#pragma unroll
    for (int fr = 0; fr < 8; ++fr) {
      int i = i0 + wm2 * 128 + fr * 16 + hi * 4;
      int b_ = i >> 10, sbase = i & 1023;
#pragma unroll
      for (int nc = 0; nc < 2; ++nc) {
        int ez = ez0 + nc * 16 + c;
        int h = ez >> 6, f = ez & 63;
        float b1_ = bias[ez], b2_ = bias[ez + 32];
        size_t obase = (size_t)((b_ * 16 + h) * 1024);
#pragma unroll
        for (int r = 0; r < 4; ++r) {
          int s = sbase + r;
          float2 cs = rt[s * 32 + f];
          float q1 = acc[fr][nc][r] + b1_;
          float q2 = acc[fr][nc + 2][r] + b2_;
          O[(obase + s) * 64 + f] = (bf16_t)((q1 * cs.x - q2 * cs.y) * scl);
          O[(obase + s) * 64 + f + 32] = (bf16_t)((q1 * cs.y + q2 * cs.x) * scl);
        }
      }
    }
  }
}

// ---------------- out projection (same engine) ----------------
__global__ __launch_bounds__(512) void k_gemm_out(
    const bf16_t* __restrict__ Og, const bf16_t* __restrict__ Wob,
    const float* __restrict__ bo, float* __restrict__ out) {
  const int bid = blockIdx.x;
  const int wg = (bid & 7) * 16 + (bid >> 3);
  const int i0 = (wg >> 2) * 256;
  const int e0 = (wg & 3) * 256;

  GEMM256_BODY(Og, Wob)

#pragma unroll
  for (int fr = 0; fr < 8; ++fr) {
    int i = i0 + wm2 * 128 + fr * 16 + hi * 4;
#pragma unroll
    for (int nc = 0; nc < 4; ++nc) {
      int e = e0 + wn4 * 64 + nc * 16 + c;
      float bv_ = bo[e];
#pragma unroll
      for (int r = 0; r < 4; ++r)
        out[(size_t)(i + r) * 1024 + e] = acc[fr][nc][r] + bv_;
    }
  }
}

// ---------------- flash attention (R5 rewrite) ----------------
// 1024 blocks x 512 thr (8 waves, 16 q each => 128 q/block). XCD-swizzled so
// 16 consecutive bh (their K/V ~2MB) stay on one XCD's L2.
// K/V LDS: lane-linear subtiles (frag read = base + lane*16, 0 conflicts),
// permutation folded into per-lane global source (m173). 3 buffers, vmcnt(2).
// Swapped ops: ST[k][q]=mfma(K,Q), O[dk][q]=mfma(V^T,P) -> all softmax state
// per-lane (q = lane&15); P via wave-private subtiled Pl (conflict-free read).
__global__ __launch_bounds__(512) void k_attn(
    const bf16_t* __restrict__ Qh, const bf16_t* __restrict__ Kh,
    const bf16_t* __restrict__ Vt, bf16_t* __restrict__ Og) {
  __shared__ alignas(16) char KL[3][8192];
  __shared__ alignas(16) char VL[3][8192];
  __shared__ alignas(16) char PL[8][2048];
  const int t = threadIdx.x;
  const int lane = t & 63, w = t >> 6;
  const int hi = lane >> 4, c = lane & 15;
  const int bid = blockIdx.x;
  const int wg = (bid & 7) * 128 + (bid >> 3);   // XCD X -> bh in [X*16, X*16+16)
  const int bh = wg >> 3, qt = wg & 7;
  const size_t base = (size_t)bh * 64 * 1024;
  const int q0 = qt * 128 + w * 16;

  // stage decode: thread t fills LDS bytes [t*16, t*16+16) of an 8KB tile;
  // subtile layout byte = fr*2048 + ks*256 + c*16  (row=fr*16+c, k=ks*8)
  const int sc = t & 15, sks = (t >> 4) & 7, sfr = t >> 7;
  const bf16_t* srcK = Kh + base + (size_t)(sfr * 16 + sc) * 64 + sks * 8;
  const bf16_t* srcV = Vt + base + (size_t)(sfr * 16 + sc) * 1024 + sks * 8;
  auto stage = [&](int b3, int kt) {
    gload_lds16(srcK + (size_t)kt * 64 * 64, &KL[b3][0] + t * 16);
    gload_lds16(srcV + kt * 64, &VL[b3][0] + t * 16);
  };

  // Q as B-fragment: lane holds Q[q0+c][kk*32 + hi*8 ..+8]  (pre-scaled)
  bf16x8 qf[2];
  qf[0] = *(const bf16x8*)&Qh[base + (size_t)(q0 + c) * 64 + hi * 8];
  qf[1] = *(const bf16x8*)&Qh[base + (size_t)(q0 + c) * 64 + 32 + hi * 8];

  f32x4 o[4] = {};
  float m = -1e30f, lsum = 0.f;

  stage(0, 0);
  stage(1, 1);
  VMCNT(2);          // tile0 resident (tile1's 2 loads may remain in flight)
  SBAR();

  char* const plw = &PL[w][0];
  for (int kt = 0; kt < 16; ++kt) {
    const int b3 = kt % 3;
    if (kt + 2 < 16) stage((kt + 2) % 3, kt + 2);

    // QK^T: ST[k][q] ; A-frag = K[ni*16+c][kk*32+hi*8..], read = base+lane*16
    const char* kb = &KL[b3][0] + lane * 16;
    f32x4 st[4] = {};
#pragma unroll
    for (int ni = 0; ni < 4; ++ni)
#pragma unroll
      for (int kk = 0; kk < 2; ++kk)
        st[ni] = mfma16(*(const bf16x8*)(kb + ni * 2048 + kk * 1024), qf[kk], st[ni]);

    // online softmax in exp2 domain; lane owns q = c, holds k = ni*16+hi*4+r
    float pmax = -1e30f;
#pragma unroll
    for (int ni = 0; ni < 4; ++ni)
#pragma unroll
      for (int r = 0; r < 4; ++r) pmax = fmaxf(pmax, st[ni][r]);
    pmax = fmaxf(pmax, __shfl_xor(pmax, 16));
    pmax = fmaxf(pmax, __shfl_xor(pmax, 32));
    float mn = fmaxf(m, pmax);
    float scale = EXP2F(m - mn);
    m = mn;
    float psum = 0.f;
#pragma unroll
    for (int ni = 0; ni < 4; ++ni) {
      union { bf16_t b[4]; unsigned long long u; } pk;
#pragma unroll
      for (int r = 0; r < 4; ++r) {
        float p = EXP2F(st[ni][r] - mn);
        psum += p;
        pk.b[r] = (bf16_t)p;
      }
      // P[q=c][k=ni*16+hi*4 ..+4] -> subtiled Pl byte:
      __builtin_memcpy(plw + (ni * 2 + (hi >> 1)) * 256 + c * 16 + (hi & 1) * 8,
                       pk.b, 8);
    }
    psum += __shfl_xor(psum, 16);
    psum += __shfl_xor(psum, 32);
    lsum = lsum * scale + psum;
    // O[dk][q=c]: per-lane rescale, no shuffles
#pragma unroll
    for (int od = 0; od < 4; ++od)
#pragma unroll
      for (int r = 0; r < 4; ++r) o[od][r] *= scale;

    // PV: O[dk][q] = mfma(A=V^T[od*16+c][k], B=P[k][q=c])
    const char* vb = &VL[b3][0] + lane * 16;
#pragma unroll
    for (int od = 0; od < 4; ++od)
#pragma unroll
      for (int kk = 0; kk < 2; ++kk) {
        bf16x8 vf = *(const bf16x8*)(vb + od * 2048 + kk * 1024);
        bf16x8 pa = *(const bf16x8*)(plw + kk * 1024 + lane * 16);
        o[od] = mfma16(vf, pa, o[od]);
      }

    if (kt < 14) { VMCNT(2); } else if (kt == 14) { VMCNT0(); }
    if (kt < 15) SBAR();
  }

  // epilogue: lane owns q = c; O rows dk = od*16 + hi*4 + r
  float invl = 1.0f / lsum;
  int b_ = bh >> 4, h = bh & 15;
  size_t rowoff = ((size_t)(b_ * 1024 + q0 + c)) * 1024 + h * 64;
#pragma unroll
  for (int od = 0; od < 4; ++od) {
    union { bf16_t b[4]; unsigned long long u; } pk;
#pragma unroll
    for (int r = 0; r < 4; ++r) pk.b[r] = (bf16_t)(o[od][r] * invl);
    __builtin_memcpy(&Og[rowoff + od * 16 + hi * 4], pk.b, 8);
  }
}

extern "C" void kernel_launch(void* const* d_in, const int* in_sizes, int n_in,
                              void* d_out, int out_size, void* d_ws, size_t ws_size,
                              hipStream_t stream) {
  const float* x = (const float*)d_in[0];
  const int* pos = (const int*)d_in[1];
  const float* Wq = (const float*)d_in[2];
  const float* bq = (const float*)d_in[3];
  const float* Wk = (const float*)d_in[4];
  const float* bk = (const float*)d_in[5];
  const float* Wv = (const float*)d_in[6];
  const float* bv = (const float*)d_in[7];
  const float* Wo = (const float*)d_in[8];
  const float* bo = (const float*)d_in[9];
  float* out = (float*)d_out;

  char* ws = (char*)d_ws;
  bf16_t* Xb = (bf16_t*)ws;
  bf16_t* Wqkv = (bf16_t*)(ws + (16u << 20));
  bf16_t* Wob = (bf16_t*)(ws + (22u << 20));
  bf16_t* Vt = (bf16_t*)(ws + (24u << 20));
  float2* rt = (float2*)(ws + (42u << 20));
  bf16_t* Qh = (bf16_t*)d_out;
  bf16_t* Kh = (bf16_t*)d_out + (size_t)8 * 1024 * 1024;
  bf16_t* Og = Xb;

  k_cast<<<8192, 256, 0, stream>>>(x, Xb, 8192 * 1024 / 4);
  k_cast<<<1024, 256, 0, stream>>>(Wq, Wqkv, 1024 * 1024 / 4);
  k_cast<<<1024, 256, 0, stream>>>(Wk, Wqkv + (size_t)1024 * 1024, 1024 * 1024 / 4);
  k_cast<<<1024, 256, 0, stream>>>(Wv, Wqkv + (size_t)2048 * 1024, 1024 * 1024 / 4);
  k_cast<<<1024, 256, 0, stream>>>(Wo, Wob, 1024 * 1024 / 4);
  k_rope_table<<<128, 256, 0, stream>>>(pos, rt);

  k_gemm_qkv<<<384, 512, 0, stream>>>(Xb, Wqkv, bq, bk, bv, rt, Qh, Kh, Vt);
  k_attn<<<1024, 512, 0, stream>>>(Qh, Kh, Vt, Og);
  k_gemm_out<<<128, 512, 0, stream>>>(Og, Wob, bo, out);
}

// Round 6
// 188.204 us; speedup vs baseline: 1.3443x; 1.0791x over previous
//
#include <hip/hip_runtime.h>
#include <hip/hip_bf16.h>

// Fused: QKV proj (+bias) -> RoPE(Q,K) -> MHA softmax -> out proj (+bias)
// B=8 S=1024 D=1024 H=16 Dk=64.
// GEMM engine (R6): BM=256 x BN=128, BK=32, 8 waves (4M x 2N, 64x64/wave),
// 4-slot LDS rotation (96KB), 3 K-tiles in flight, vmcnt(6) counted waits,
// lane-linear subtiled LDS (0 conflicts), 1 phase (16 MFMA) per K-tile.
// QKV grid 768 = 3 exact rounds; out-proj 256 = 1 round. Attn = R5 (verified).

typedef __bf16 bf16_t;
typedef __bf16 bf16x8 __attribute__((ext_vector_type(8)));
typedef float  f32x4  __attribute__((ext_vector_type(4)));

static __device__ __forceinline__ f32x4 mfma16(bf16x8 a, bf16x8 b, f32x4 c) {
  return __builtin_amdgcn_mfma_f32_16x16x32_bf16(a, b, c, 0, 0, 0);
}
static __device__ __forceinline__ void gload_lds16(const void* g, void* l) {
  __builtin_amdgcn_global_load_lds((const __attribute__((address_space(1))) void*)g,
                                   (__attribute__((address_space(3))) void*)l,
                                   16, 0, 0);
}
#define VMCNT(n) asm volatile("s_waitcnt vmcnt(" #n ")" ::: "memory")
#define VMCNT0() asm volatile("s_waitcnt vmcnt(0)" ::: "memory")
#define LGKM0()  do { asm volatile("s_waitcnt lgkmcnt(0)" ::: "memory"); \
                      __builtin_amdgcn_sched_barrier(0); } while (0)
#define SBAR() do { __builtin_amdgcn_sched_barrier(0); __builtin_amdgcn_s_barrier(); \
                    __builtin_amdgcn_sched_barrier(0); } while (0)

#if __has_builtin(__builtin_amdgcn_exp2f)
#define EXP2F(x) __builtin_amdgcn_exp2f(x)
#else
#define EXP2F(x) exp2f(x)
#endif

// ---------------- prep kernels ----------------
__global__ void k_cast(const float* __restrict__ s, bf16_t* __restrict__ d, int n4) {
  int i = blockIdx.x * 256 + threadIdx.x;
  if (i >= n4) return;
  float4 v = reinterpret_cast<const float4*>(s)[i];
  union { bf16_t b[4]; unsigned long long u; } pk;
  pk.b[0] = (bf16_t)v.x; pk.b[1] = (bf16_t)v.y;
  pk.b[2] = (bf16_t)v.z; pk.b[3] = (bf16_t)v.w;
  reinterpret_cast<unsigned long long*>(d)[i] = pk.u;
}

// 4 weight matrices (1Mi elements each) -> contiguous bf16 region
__global__ void k_cast_w(const float* __restrict__ w0, const float* __restrict__ w1,
                         const float* __restrict__ w2, const float* __restrict__ w3,
                         bf16_t* __restrict__ dst) {
  int z = blockIdx.y;
  const float* s = (z == 0) ? w0 : (z == 1) ? w1 : (z == 2) ? w2 : w3;
  int i = blockIdx.x * 256 + threadIdx.x;   // 262144 float4 per matrix
  float4 v = reinterpret_cast<const float4*>(s)[i];
  union { bf16_t b[4]; unsigned long long u; } pk;
  pk.b[0] = (bf16_t)v.x; pk.b[1] = (bf16_t)v.y;
  pk.b[2] = (bf16_t)v.z; pk.b[3] = (bf16_t)v.w;
  reinterpret_cast<unsigned long long*>(dst + (size_t)z * 1048576)[i] = pk.u;
}

__global__ void k_rope_table(const int* __restrict__ pos, float2* __restrict__ rt) {
  int s = blockIdx.x * 8 + (threadIdx.x >> 5);
  int f = threadIdx.x & 31;
  float p = (float)pos[s];
  float inv = powf(10000.0f, -(float)(2 * f) / 64.0f);
  float a = p * inv;
  rt[s * 32 + f] = make_float2(cosf(a), sinf(a));
}

// ============ BK=32 GEMM body: BM=256, BN=128, 32 K-tiles, 4 LDS slots ========
// Slot (24576B): A 16KB [group g(16) x ks(4) x c(16) x 16B], B 8KB [g(8)...].
//   A frag (wm4,fr): byte = (wm4*4+fr)*1024 + lane*16   (lane-linear, 0-conflict)
//   B frag (wn2,nc): byte = 16384 + (wn2*4+nc)*1024 + lane*16
// Stage thread map: slot byte s_*16, s_ = l*512+t (A: l=0,1; B: s_=t);
//   row = (s_>>6)*16 + (s_&15), k = ((s_>>4)&3)*8  -> per-lane global src.
// Pipeline: stage(j+3) during tile j; vmcnt(6) end-of-tile (2 tiles x 3 loads
//   outstanding) guarantees tile j+1 resident; slot (j+3)&3 = (j-1)&3 whose
//   reads were drained (per-wave lgkm0) before tile j-1's trailing barrier.
#define PHASE(J, STAGE_STMT, WAIT_STMT)                                        \
  do {                                                                         \
    const char* la = laB + ((J) & 3) * 24576;                                  \
    const char* lb = lbB + ((J) & 3) * 24576;                                  \
    bf16x8 af[4], bg[4];                                                       \
    _Pragma("unroll") for (int fr = 0; fr < 4; ++fr)                           \
      af[fr] = *(const bf16x8*)(la + fr * 1024);                               \
    _Pragma("unroll") for (int nc = 0; nc < 4; ++nc)                           \
      bg[nc] = *(const bf16x8*)(lb + nc * 1024);                               \
    STAGE_STMT;                                                                \
    SBAR();                                                                    \
    LGKM0();                                                                   \
    __builtin_amdgcn_s_setprio(1);                                             \
    _Pragma("unroll") for (int fr = 0; fr < 4; ++fr)                           \
      _Pragma("unroll") for (int nc = 0; nc < 4; ++nc)                         \
        acc[fr][nc] = mfma16(af[fr], bg[nc], acc[fr][nc]);                     \
    __builtin_amdgcn_s_setprio(0);                                             \
    WAIT_STMT;                                                                 \
    SBAR();                                                                    \
  } while (0)

#define GEMM_BK32_BODY(Aptr, Bptr)                                             \
  __shared__ alignas(16) char LDSbuf[98304];                                   \
  const int t = threadIdx.x;                                                   \
  const int lane = t & 63, w = t >> 6;                                         \
  const int hi = lane >> 4, c = lane & 15;                                     \
  const int wm4 = w >> 1, wn2 = w & 1;                                         \
  const bf16_t* gA[2];                                                         \
  _Pragma("unroll") for (int l = 0; l < 2; ++l) {                              \
    int s_ = l * 512 + t;                                                      \
    gA[l] = (Aptr) + (size_t)(i0 + ((s_ >> 6) << 4) + (s_ & 15)) * 1024 +      \
            ((s_ >> 4) & 3) * 8;                                               \
  }                                                                            \
  const bf16_t* gB = (Bptr) + (size_t)(e0 + ((t >> 6) << 4) + (t & 15)) * 1024 \
                     + ((t >> 4) & 3) * 8;                                     \
  auto stage = [&](int slot, int kt) {                                         \
    char* d0 = LDSbuf + slot * 24576 + t * 16;                                 \
    gload_lds16(gA[0] + kt * 32, d0);                                          \
    gload_lds16(gA[1] + kt * 32, d0 + 8192);                                   \
    gload_lds16(gB + kt * 32, d0 + 16384);                                     \
  };                                                                           \
  f32x4 acc[4][4] = {};                                                        \
  stage(0, 0); stage(1, 1); stage(2, 2);                                       \
  VMCNT(6);                                                                    \
  SBAR();                                                                      \
  const char* laB = LDSbuf + wm4 * 4096 + lane * 16;                           \
  const char* lbB = LDSbuf + 16384 + wn2 * 4096 + lane * 16;                   \
  _Pragma("unroll 4")                                                          \
  for (int j = 0; j < 28; ++j) {                                               \
    PHASE(j, stage((j + 3) & 3, j + 3), VMCNT(6));                             \
  }                                                                            \
  PHASE(28, stage(3, 31), VMCNT(6));                                           \
  PHASE(29, (void)0, VMCNT(3));                                                \
  PHASE(30, (void)0, VMCNT0());                                                \
  PHASE(31, (void)0, (void)0);

// ---------------- fused QKV GEMM: N=3072 (Wq|Wk|Wv concat) ----------------
// 768 blocks = 32 m x 24 n; XCD gets 4 consecutive m x all 24 n.
__global__ __launch_bounds__(512) void k_gemm_qkv(
    const bf16_t* __restrict__ Xb, const bf16_t* __restrict__ Wqkv,
    const float* __restrict__ bq, const float* __restrict__ bk,
    const float* __restrict__ bv, const float2* __restrict__ rt,
    bf16_t* __restrict__ Qh, bf16_t* __restrict__ Kh, bf16_t* __restrict__ Vt) {
  const int bid = blockIdx.x;
  const int wg = (bid & 7) * 96 + (bid >> 3);
  const int i0 = (wg / 24) * 256;
  const int e0 = (wg % 24) * 128;

  GEMM_BK32_BODY(Xb, Wqkv)

  // Epilogue: one head per wave (64-col window at ez0).
  const int z = e0 >> 10;                       // 0:Q 1:K 2:V
  const int ez0 = (e0 & 1023) + wn2 * 64;       // multiple of 64
  const int h = ez0 >> 6;
  const float* bias = (z == 0) ? bq : (z == 1) ? bk : bv;
  if (z == 2) {
#pragma unroll
    for (int fr = 0; fr < 4; ++fr) {
      int i = i0 + wm4 * 64 + fr * 16 + hi * 4;
      int b_ = i >> 10, s = i & 1023;
#pragma unroll
      for (int nc = 0; nc < 4; ++nc) {
        int dk = nc * 16 + c;
        float bv_ = bias[ez0 + dk];
        union { bf16_t b[4]; unsigned long long u; } pk;
#pragma unroll
        for (int r = 0; r < 4; ++r) pk.b[r] = (bf16_t)(acc[fr][nc][r] + bv_);
        __builtin_memcpy(&Vt[((size_t)((b_ * 16 + h) * 64 + dk)) * 1024 + s], pk.b, 8);
      }
    }
  } else {
    bf16_t* O = (z == 0) ? Qh : Kh;
    // Q folds 1/sqrt(64) * log2(e): attn softmax runs in exp2 domain.
    const float scl = (z == 0) ? 0.18033688011112042f : 1.0f;
#pragma unroll
    for (int fr = 0; fr < 4; ++fr) {
      int i = i0 + wm4 * 64 + fr * 16 + hi * 4;
      int b_ = i >> 10, sbase = i & 1023;
      size_t obase = (size_t)((b_ * 16 + h) * 1024);
#pragma unroll
      for (int nc = 0; nc < 2; ++nc) {          // f<32; partner f+32 = frag nc+2
        int f = nc * 16 + c;
        float b1_ = bias[ez0 + f], b2_ = bias[ez0 + f + 32];
#pragma unroll
        for (int r = 0; r < 4; ++r) {
          int s = sbase + r;
          float2 cs = rt[s * 32 + f];
          float q1 = acc[fr][nc][r] + b1_;
          float q2 = acc[fr][nc + 2][r] + b2_;
          O[(obase + s) * 64 + f] = (bf16_t)((q1 * cs.x - q2 * cs.y) * scl);
          O[(obase + s) * 64 + f + 32] = (bf16_t)((q1 * cs.y + q2 * cs.x) * scl);
        }
      }
    }
  }
}

// ---------------- out projection (same engine): 256 blocks = 32m x 8n ------
__global__ __launch_bounds__(512) void k_gemm_out(
    const bf16_t* __restrict__ Og, const bf16_t* __restrict__ Wob,
    const float* __restrict__ bo, float* __restrict__ out) {
  const int bid = blockIdx.x;
  const int wg = (bid & 7) * 32 + (bid >> 3);
  const int i0 = (wg >> 3) * 256;
  const int e0 = (wg & 7) * 128;

  GEMM_BK32_BODY(Og, Wob)

#pragma unroll
  for (int fr = 0; fr < 4; ++fr) {
    int i = i0 + wm4 * 64 + fr * 16 + hi * 4;
#pragma unroll
    for (int nc = 0; nc < 4; ++nc) {
      int e = e0 + wn2 * 64 + nc * 16 + c;
      float bv_ = bo[e];
#pragma unroll
      for (int r = 0; r < 4; ++r)
        out[(size_t)(i + r) * 1024 + e] = acc[fr][nc][r] + bv_;
    }
  }
}

// ---------------- flash attention (R5, verified) ----------------
__global__ __launch_bounds__(512) void k_attn(
    const bf16_t* __restrict__ Qh, const bf16_t* __restrict__ Kh,
    const bf16_t* __restrict__ Vt, bf16_t* __restrict__ Og) {
  __shared__ alignas(16) char KL[3][8192];
  __shared__ alignas(16) char VL[3][8192];
  __shared__ alignas(16) char PL[8][2048];
  const int t = threadIdx.x;
  const int lane = t & 63, w = t >> 6;
  const int hi = lane >> 4, c = lane & 15;
  const int bid = blockIdx.x;
  const int wg = (bid & 7) * 128 + (bid >> 3);
  const int bh = wg >> 3, qt = wg & 7;
  const size_t base = (size_t)bh * 64 * 1024;
  const int q0 = qt * 128 + w * 16;

  const int sc = t & 15, sks = (t >> 4) & 7, sfr = t >> 7;
  const bf16_t* srcK = Kh + base + (size_t)(sfr * 16 + sc) * 64 + sks * 8;
  const bf16_t* srcV = Vt + base + (size_t)(sfr * 16 + sc) * 1024 + sks * 8;
  auto stage = [&](int b3, int kt) {
    gload_lds16(srcK + (size_t)kt * 64 * 64, &KL[b3][0] + t * 16);
    gload_lds16(srcV + kt * 64, &VL[b3][0] + t * 16);
  };

  bf16x8 qf[2];
  qf[0] = *(const bf16x8*)&Qh[base + (size_t)(q0 + c) * 64 + hi * 8];
  qf[1] = *(const bf16x8*)&Qh[base + (size_t)(q0 + c) * 64 + 32 + hi * 8];

  f32x4 o[4] = {};
  float m = -1e30f, lsum = 0.f;

  stage(0, 0);
  stage(1, 1);
  VMCNT(2);
  SBAR();

  char* const plw = &PL[w][0];
  for (int kt = 0; kt < 16; ++kt) {
    const int b3 = kt % 3;
    if (kt + 2 < 16) stage((kt + 2) % 3, kt + 2);

    const char* kb = &KL[b3][0] + lane * 16;
    f32x4 st[4] = {};
#pragma unroll
    for (int ni = 0; ni < 4; ++ni)
#pragma unroll
      for (int kk = 0; kk < 2; ++kk)
        st[ni] = mfma16(*(const bf16x8*)(kb + ni * 2048 + kk * 1024), qf[kk], st[ni]);

    float pmax = -1e30f;
#pragma unroll
    for (int ni = 0; ni < 4; ++ni)
#pragma unroll
      for (int r = 0; r < 4; ++r) pmax = fmaxf(pmax, st[ni][r]);
    pmax = fmaxf(pmax, __shfl_xor(pmax, 16));
    pmax = fmaxf(pmax, __shfl_xor(pmax, 32));
    float mn = fmaxf(m, pmax);
    float scale = EXP2F(m - mn);
    m = mn;
    float psum = 0.f;
#pragma unroll
    for (int ni = 0; ni < 4; ++ni) {
      union { bf16_t b[4]; unsigned long long u; } pk;
#pragma unroll
      for (int r = 0; r < 4; ++r) {
        float p = EXP2F(st[ni][r] - mn);
        psum += p;
        pk.b[r] = (bf16_t)p;
      }
      __builtin_memcpy(plw + (ni * 2 + (hi >> 1)) * 256 + c * 16 + (hi & 1) * 8,
                       pk.b, 8);
    }
    psum += __shfl_xor(psum, 16);
    psum += __shfl_xor(psum, 32);
    lsum = lsum * scale + psum;
#pragma unroll
    for (int od = 0; od < 4; ++od)
#pragma unroll
      for (int r = 0; r < 4; ++r) o[od][r] *= scale;

    const char* vb = &VL[b3][0] + lane * 16;
#pragma unroll
    for (int od = 0; od < 4; ++od)
#pragma unroll
      for (int kk = 0; kk < 2; ++kk) {
        bf16x8 vf = *(const bf16x8*)(vb + od * 2048 + kk * 1024);
        bf16x8 pa = *(const bf16x8*)(plw + kk * 1024 + lane * 16);
        o[od] = mfma16(vf, pa, o[od]);
      }

    if (kt < 14) { VMCNT(2); } else if (kt == 14) { VMCNT0(); }
    if (kt < 15) SBAR();
  }

  float invl = 1.0f / lsum;
  int b_ = bh >> 4, h = bh & 15;
  size_t rowoff = ((size_t)(b_ * 1024 + q0 + c)) * 1024 + h * 64;
#pragma unroll
  for (int od = 0; od < 4; ++od) {
    union { bf16_t b[4]; unsigned long long u; } pk;
#pragma unroll
    for (int r = 0; r < 4; ++r) pk.b[r] = (bf16_t)(o[od][r] * invl);
    __builtin_memcpy(&Og[rowoff + od * 16 + hi * 4], pk.b, 8);
  }
}

extern "C" void kernel_launch(void* const* d_in, const int* in_sizes, int n_in,
                              void* d_out, int out_size, void* d_ws, size_t ws_size,
                              hipStream_t stream) {
  const float* x = (const float*)d_in[0];
  const int* pos = (const int*)d_in[1];
  const float* Wq = (const float*)d_in[2];
  const float* bq = (const float*)d_in[3];
  const float* Wk = (const float*)d_in[4];
  const float* bk = (const float*)d_in[5];
  const float* Wv = (const float*)d_in[6];
  const float* bv = (const float*)d_in[7];
  const float* Wo = (const float*)d_in[8];
  const float* bo = (const float*)d_in[9];
  float* out = (float*)d_out;

  // ws: [0,16M) Xb (reused as Og) | [16M,24M) Wqkv(6M)+Wob(2M) contiguous
  //     [24M,40M) Vt | [42M,..) rope table.  Q,K live in d_out (32MB).
  char* ws = (char*)d_ws;
  bf16_t* Xb = (bf16_t*)ws;
  bf16_t* Wqkv = (bf16_t*)(ws + (16u << 20));
  bf16_t* Wob = (bf16_t*)(ws + (22u << 20));
  bf16_t* Vt = (bf16_t*)(ws + (24u << 20));
  float2* rt = (float2*)(ws + (42u << 20));
  bf16_t* Qh = (bf16_t*)d_out;
  bf16_t* Kh = (bf16_t*)d_out + (size_t)8 * 1024 * 1024;
  bf16_t* Og = Xb;

  k_cast<<<8192, 256, 0, stream>>>(x, Xb, 8192 * 1024 / 4);
  k_cast_w<<<dim3(1024, 4), 256, 0, stream>>>(Wq, Wk, Wv, Wo, Wqkv);
  k_rope_table<<<128, 256, 0, stream>>>(pos, rt);

  k_gemm_qkv<<<768, 512, 0, stream>>>(Xb, Wqkv, bq, bk, bv, rt, Qh, Kh, Vt);
  k_attn<<<1024, 512, 0, stream>>>(Qh, Kh, Vt, Og);
  k_gemm_out<<<256, 512, 0, stream>>>(Og, Wob, bo, out);
}